// Round 1
// baseline (27380.240 us; speedup 1.0000x reference)
//
#include <hip/hip_runtime.h>

#define B_ 128
#define T_ 256
#define I_ 512
#define H_ 1024

#define BM 64      // batch rows per workgroup
#define NT 8       // n-columns per tile
#define CT 32      // 4 gates * NT
#define BK 32      // K-step

#define AS_STRIDE 66   // [BK][BM+2]  -> 2-way max write conflicts
#define WS_STRIDE 36   // [BK][CT+4]  -> 4-way max write conflicts, 16B-aligned rows

__device__ __forceinline__ float fsigmoid(float x) { return 1.0f / (1.0f + __expf(-x)); }
// robust tanh: no NaN at +/-inf of exp
__device__ __forceinline__ float ftanh(float x) { return 1.0f - 2.0f / (__expf(2.0f * x) + 1.0f); }

// Fused: gates = A1 @ Wih^T + hprev @ Whh^T + bih + bhh ; LSTM cell update.
// A1 rows are [b0..b0+127] with row stride a1_stride; K1 = A1 depth.
__global__ __launch_bounds__(256) void lstm_step(
    const float* __restrict__ A1, long a1_stride, int K1,
    const float* __restrict__ hprev,
    const float* __restrict__ Wih, const float* __restrict__ Whh,
    const float* __restrict__ bih, const float* __restrict__ bhh,
    float* __restrict__ cbuf, float* __restrict__ hout,
    float* yout, long y_stride)
{
    __shared__ float As[BK][AS_STRIDE];  // [k][b]  transposed A tile
    __shared__ float Ws[BK][WS_STRIDE];  // [k][cc] transposed W tile

    const int tid = threadIdx.x;
    const int n0 = blockIdx.x * NT;   // hidden-col base
    const int b0 = blockIdx.y * BM;   // batch base

    const int tb = tid >> 3;   // 0..31  : b-pair index (rows 2tb, 2tb+1)
    const int tc = tid & 7;    // 0..7   : c-quad index (cols 4tc..4tc+3)

    const int lr = tid >> 3;   // 0..31  : load row (A) / tile row cc (W)
    const int lk = tid & 7;    // 0..7   : load k-quad

    // weight tile row cc -> global weight row j = gate*H + n
    const long wj = (long)(lr >> 3) * H_ + n0 + (lr & 7);

    float acc[2][4] = {{0.f, 0.f, 0.f, 0.f}, {0.f, 0.f, 0.f, 0.f}};

    #pragma unroll 1
    for (int ph = 0; ph < 2; ++ph) {
        const float* Ap = (ph == 0) ? A1 : hprev;
        const long   as = (ph == 0) ? a1_stride : (long)H_;
        const float* W  = (ph == 0) ? Wih : Whh;
        const int    K  = (ph == 0) ? K1 : H_;

        const float* arow0 = Ap + (long)(b0 + lr) * as + 4 * lk;
        const float* arow1 = Ap + (long)(b0 + lr + 32) * as + 4 * lk;
        const float* wrow  = W + wj * K + 4 * lk;

        // register prefetch of tile 0
        float4 ra0 = *(const float4*)(arow0);
        float4 ra1 = *(const float4*)(arow1);
        float4 rw  = *(const float4*)(wrow);

        for (int k0 = 0; k0 < K; k0 += BK) {
            __syncthreads();   // previous iteration's readers done
            {
                const int kk = 4 * lk;
                As[kk + 0][lr] = ra0.x;  As[kk + 1][lr] = ra0.y;
                As[kk + 2][lr] = ra0.z;  As[kk + 3][lr] = ra0.w;
                As[kk + 0][lr + 32] = ra1.x;  As[kk + 1][lr + 32] = ra1.y;
                As[kk + 2][lr + 32] = ra1.z;  As[kk + 3][lr + 32] = ra1.w;
                Ws[kk + 0][lr] = rw.x;  Ws[kk + 1][lr] = rw.y;
                Ws[kk + 2][lr] = rw.z;  Ws[kk + 3][lr] = rw.w;
            }
            __syncthreads();
            const int kn = k0 + BK;
            if (kn < K) {   // prefetch next tile; latency overlaps compute below
                ra0 = *(const float4*)(arow0 + kn);
                ra1 = *(const float4*)(arow1 + kn);
                rw  = *(const float4*)(wrow + kn);
            }
            #pragma unroll
            for (int k = 0; k < BK; ++k) {
                float2 a = *(const float2*)&As[k][2 * tb];
                float4 w = *(const float4*)&Ws[k][4 * tc];
                acc[0][0] = fmaf(a.x, w.x, acc[0][0]);
                acc[0][1] = fmaf(a.x, w.y, acc[0][1]);
                acc[0][2] = fmaf(a.x, w.z, acc[0][2]);
                acc[0][3] = fmaf(a.x, w.w, acc[0][3]);
                acc[1][0] = fmaf(a.y, w.x, acc[1][0]);
                acc[1][1] = fmaf(a.y, w.y, acc[1][1]);
                acc[1][2] = fmaf(a.y, w.z, acc[1][2]);
                acc[1][3] = fmaf(a.y, w.w, acc[1][3]);
            }
        }
    }

    // ---- epilogue: regroup gates per (b, n) via LDS, then cell update ----
    __syncthreads();
    float* gs = &As[0][0];   // reuse as [64][33] = 2112 floats (fits exactly)
    #pragma unroll
    for (int bi = 0; bi < 2; ++bi)
        #pragma unroll
        for (int ci = 0; ci < 4; ++ci)
            gs[(2 * tb + bi) * 33 + 4 * tc + ci] = acc[bi][ci];
    __syncthreads();

    const int dn = tid & 7;          // n fast-varying -> 32B-coalesced global access
    const int bq = tid >> 3;         // 0..31
    const int n  = n0 + dn;
    #pragma unroll
    for (int s = 0; s < 2; ++s) {
        const int b = bq + 32 * s;
        float xi = gs[b * 33 +      dn] + bih[n]          + bhh[n];
        float xf = gs[b * 33 +  8 + dn] + bih[H_ + n]     + bhh[H_ + n];
        float xg = gs[b * 33 + 16 + dn] + bih[2 * H_ + n] + bhh[2 * H_ + n];
        float xo = gs[b * 33 + 24 + dn] + bih[3 * H_ + n] + bhh[3 * H_ + n];
        const long idx = (long)(b0 + b) * H_ + n;
        const float c_old = cbuf[idx];
        const float cn = fsigmoid(xf) * c_old + fsigmoid(xi) * ftanh(xg);
        const float hn = fsigmoid(xo) * ftanh(cn);
        cbuf[idx] = cn;
        hout[idx] = hn;
        if (yout) yout[(long)(b0 + b) * y_stride + n] = hn;
    }
}

extern "C" void kernel_launch(void* const* d_in, const int* in_sizes, int n_in,
                              void* d_out, int out_size, void* d_ws, size_t ws_size,
                              hipStream_t stream) {
    const float* x    = (const float*)d_in[0];
    const float* Wih0 = (const float*)d_in[1];
    const float* Whh0 = (const float*)d_in[2];
    const float* bih0 = (const float*)d_in[3];
    const float* bhh0 = (const float*)d_in[4];
    const float* Wih1 = (const float*)d_in[5];
    const float* Whh1 = (const float*)d_in[6];
    const float* bih1 = (const float*)d_in[7];
    const float* bhh1 = (const float*)d_in[8];
    float* out = (float*)d_out;

    const size_t BH = (size_t)B_ * H_;
    float* ws  = (float*)d_ws;
    float* h0a = ws;            // layer0 h ping
    float* h0b = ws + BH;       // layer0 h pong
    float* c0  = ws + 2 * BH;   // layer0 c (in-place)
    float* h1a = ws + 3 * BH;
    float* h1b = ws + 4 * BH;
    float* c1  = ws + 5 * BH;
    // zero initial states every call (deterministic; ws is poisoned once)
    hipMemsetAsync(d_ws, 0, 6 * BH * sizeof(float), stream);

    dim3 grid(H_ / NT, B_ / BM);   // (128, 2) = 256 workgroups
    dim3 block(256);
    for (int t = 0; t < T_; ++t) {
        float* h0in  = (t & 1) ? h0b : h0a;
        float* h0out = (t & 1) ? h0a : h0b;
        float* h1in  = (t & 1) ? h1b : h1a;
        float* h1out = (t & 1) ? h1a : h1b;
        // layer 0: input x_t [128 x 512], row stride T*I
        lstm_step<<<grid, block, 0, stream>>>(
            x + (size_t)t * I_, (long)T_ * I_, I_,
            h0in, Wih0, Whh0, bih0, bhh0, c0, h0out, nullptr, 0);
        // layer 1: input h0out [128 x 1024]; also writes y[:, t, :]
        lstm_step<<<grid, block, 0, stream>>>(
            h0out, (long)H_, H_,
            h1in, Wih1, Whh1, bih1, bhh1, c1, h1out,
            out + (size_t)t * H_, (long)T_ * H_);
    }
}

// Round 2
// 5822.224 us; speedup vs baseline: 4.7027x; 4.7027x over previous
//
#include <hip/hip_runtime.h>

#define B_ 128
#define T_ 256
#define I_ 512
#define H_ 1024

typedef _Float16 f16;
typedef _Float16 v8h __attribute__((ext_vector_type(8)));
typedef float v16f __attribute__((ext_vector_type(16)));

__device__ __forceinline__ float fsigmoid(float x) { return 1.0f / (1.0f + __expf(-x)); }
__device__ __forceinline__ float ftanh(float x) { return 1.0f - 2.0f / (__expf(2.0f * x) + 1.0f); }

// ---------------- conversion kernels ----------------
__global__ void k_f32_to_f16(const float* __restrict__ in, f16* __restrict__ out, int n) {
    int i = blockIdx.x * blockDim.x + threadIdx.x;
    int st = gridDim.x * blockDim.x;
    for (; i < n; i += st) out[i] = (f16)in[i];
}
__global__ void k_split_f16(const float* __restrict__ in, f16* __restrict__ hi,
                            f16* __restrict__ lo, int n) {
    int i = blockIdx.x * blockDim.x + threadIdx.x;
    int st = gridDim.x * blockDim.x;
    for (; i < n; i += st) {
        float v = in[i];
        f16 h = (f16)v;
        hi[i] = h;
        lo[i] = (f16)(v - (float)h);
    }
}
__global__ void k_bias_sum(const float* __restrict__ a, const float* __restrict__ b,
                           float* __restrict__ o, int n) {
    int i = blockIdx.x * blockDim.x + threadIdx.x;
    int st = gridDim.x * blockDim.x;
    for (; i < n; i += st) o[i] = a[i] + b[i];
}

// ---------------- fused MFMA step: layer0[t] (slot 0) || layer1[t-1] (slot 1) ----------------
// grid.x = 256: bx = slot*128 + m*64 + nt  (keeps nt%8 == bx%8 -> stable XCD->weight-slice map)
__global__ __launch_bounds__(256) void lstm_step_mfma(
    int t,
    const f16* __restrict__ xh, const f16* __restrict__ xl,
    const f16* __restrict__ W0i, const f16* __restrict__ W0h,
    const f16* __restrict__ W1i, const f16* __restrict__ W1h,
    const float* __restrict__ bsum0, const float* __restrict__ bsum1,
    f16* __restrict__ h0, f16* __restrict__ h1,
    float* __restrict__ c0, float* __restrict__ c1,
    float* __restrict__ out)
{
    __shared__ __align__(16) unsigned char lds[24576];  // A hi 8K | A lo 8K | B 8K ; epilogue gs 64x68 f32

    const int bx = blockIdx.x;
    const int slot = bx >> 7;
    const int m0 = ((bx >> 6) & 1) * 64;
    const int nt = bx & 63;

    if (slot == 0 && t >= T_) return;
    if (slot == 1 && t == 0) return;
    const int tau = slot ? t - 1 : t;

    const size_t BH = (size_t)B_ * H_;
    const f16 *A0h, *A0l, *A1h_, *A1l_, *Wi, *Wh;
    const float* bs;
    float* cp;
    f16 *hoh, *hol;
    float* yp = nullptr;
    long rs0;
    int K0;
    if (slot == 0) {
        A0h = xh + (size_t)tau * I_;
        A0l = xl + (size_t)tau * I_;
        rs0 = (long)T_ * I_;
        K0 = I_;
        const int pb = (tau + 1) & 1;      // h0[tau-1]
        A1h_ = h0 + (size_t)pb * 2 * BH;
        A1l_ = A1h_ + BH;
        Wi = W0i; Wh = W0h; bs = bsum0; cp = c0;
        f16* ob = h0 + (size_t)(tau & 1) * 2 * BH;
        hoh = ob; hol = ob + BH;
    } else {
        const int ib = tau & 1;            // h0[tau] (written by launch t-1, slot 0)
        A0h = h0 + (size_t)ib * 2 * BH;
        A0l = A0h + BH;
        rs0 = H_;
        K0 = H_;
        const int pb = (tau + 1) & 1;      // h1[tau-1]
        A1h_ = h1 + (size_t)pb * 2 * BH;
        A1l_ = A1h_ + BH;
        Wi = W1i; Wh = W1h; bs = bsum1; cp = c1;
        f16* ob = h1 + (size_t)(tau & 1) * 2 * BH;
        hoh = ob; hol = ob + BH;
        yp = out + (size_t)tau * H_;
    }

    const int tid = threadIdx.x;
    const int lane = tid & 63;
    const int wave = tid >> 6;
    const int wm = wave >> 1, wn = wave & 1;
    const int l31 = lane & 31, khi = lane >> 5;

    // staging map: thread -> (row, 16B slot); row and row+32
    const int srow = tid >> 3;   // 0..31
    const int ssl = tid & 7;     // 0..7
    const int j0 = ((srow >> 4) * H_) + nt * 16 + (srow & 15);   // W rows, gates 0..1 (+2H for 2..3)

    uint4* Asv = (uint4*)lds;             // hi plane [64][8]; lo plane at +512
    uint4* Bsv = (uint4*)(lds + 16384);   // [64][8]
    const int wsl = ssl ^ (srow & 7);     // XOR swizzle (same for srow+32)
    const int aidx0 = srow * 8 + wsl;
    const int aidx1 = (srow + 32) * 8 + wsl;

    v16f acc = {};

#pragma unroll 1
    for (int ph = 0; ph < 2; ++ph) {
        const f16* Ah = ph ? A1h_ : A0h;
        const f16* Al = ph ? A1l_ : A0l;
        const long rs = ph ? H_ : rs0;
        const f16* W = ph ? Wh : Wi;
        const int K = ph ? H_ : K0;

        const f16* pah0 = Ah + (size_t)(m0 + srow) * rs + ssl * 8;
        const f16* pah1 = Ah + (size_t)(m0 + srow + 32) * rs + ssl * 8;
        const f16* pal0 = Al + (size_t)(m0 + srow) * rs + ssl * 8;
        const f16* pal1 = Al + (size_t)(m0 + srow + 32) * rs + ssl * 8;
        const f16* pw0 = W + (size_t)j0 * K + ssl * 8;
        const f16* pw1 = W + ((size_t)j0 + 2 * H_) * K + ssl * 8;

        uint4 r0 = *(const uint4*)pah0;
        uint4 r1 = *(const uint4*)pah1;
        uint4 r2 = *(const uint4*)pal0;
        uint4 r3 = *(const uint4*)pal1;
        uint4 r4 = *(const uint4*)pw0;
        uint4 r5 = *(const uint4*)pw1;

        for (int k0 = 0; k0 < K; k0 += 64) {
            __syncthreads();   // previous chunk's readers done
            Asv[aidx0] = r0; Asv[aidx1] = r1;
            Asv[512 + aidx0] = r2; Asv[512 + aidx1] = r3;
            Bsv[aidx0] = r4; Bsv[aidx1] = r5;
            __syncthreads();
            const int kn = k0 + 64;
            if (kn < K) {      // prefetch next chunk; latency hides under MFMAs
                r0 = *(const uint4*)(pah0 + kn);
                r1 = *(const uint4*)(pah1 + kn);
                r2 = *(const uint4*)(pal0 + kn);
                r3 = *(const uint4*)(pal1 + kn);
                r4 = *(const uint4*)(pw0 + kn);
                r5 = *(const uint4*)(pw1 + kn);
            }
            const int arow = wm * 32 + l31;
            const int brow = wn * 32 + l31;
#pragma unroll
            for (int ks = 0; ks < 4; ++ks) {
                const int s = ks * 2 + khi;
                const v8h a_h = *(const v8h*)(lds + (size_t)(arow * 8 + (s ^ (arow & 7))) * 16);
                const v8h a_l = *(const v8h*)(lds + 8192 + (size_t)(arow * 8 + (s ^ (arow & 7))) * 16);
                const v8h bfr = *(const v8h*)(lds + 16384 + (size_t)(brow * 8 + (s ^ (brow & 7))) * 16);
                acc = __builtin_amdgcn_mfma_f32_32x32x16_f16(a_h, bfr, acc, 0, 0, 0);
                acc = __builtin_amdgcn_mfma_f32_32x32x16_f16(a_l, bfr, acc, 0, 0, 0);
            }
        }
    }

    // ---- epilogue: acc -> LDS regroup -> cell update ----
    __syncthreads();
    float* gs = (float*)lds;   // [64][68]
    {
        const int colw = wn * 32 + l31;
#pragma unroll
        for (int r = 0; r < 16; ++r) {
            const int row = wm * 32 + (r & 3) + 8 * (r >> 2) + 4 * khi;
            gs[row * 68 + colw] = acc[r];
        }
    }
    __syncthreads();

    const int rr = tid >> 4, nn = tid & 15;
    const int n = nt * 16 + nn;
    const float bi_ = bs[n], bf_ = bs[H_ + n], bg_ = bs[2 * H_ + n], bo_ = bs[3 * H_ + n];
#pragma unroll
    for (int s4 = 0; s4 < 4; ++s4) {
        const int row = rr + 16 * s4;
        const int b = m0 + row;
        const float xi = gs[row * 68 + nn] + bi_;
        const float xf = gs[row * 68 + 16 + nn] + bf_;
        const float xg = gs[row * 68 + 32 + nn] + bg_;
        const float xo = gs[row * 68 + 48 + nn] + bo_;
        const size_t ix = (size_t)b * H_ + n;
        const float co = cp[ix];
        const float cn = fsigmoid(xf) * co + fsigmoid(xi) * ftanh(xg);
        const float hn = fsigmoid(xo) * ftanh(cn);
        cp[ix] = cn;
        const f16 hh = (f16)hn;
        hoh[ix] = hh;
        hol[ix] = (f16)(hn - (float)hh);
        if (yp) yp[(size_t)b * T_ * H_ + n] = hn;
    }
}

// ---------------- fp32 fallback (round-1 verified) ----------------
#define BM 64
#define NT 8
#define AS_STRIDE 66
#define WS_STRIDE 36

__global__ __launch_bounds__(256) void lstm_step(
    const float* __restrict__ A1, long a1_stride, int K1,
    const float* __restrict__ hprev,
    const float* __restrict__ Wih, const float* __restrict__ Whh,
    const float* __restrict__ bih, const float* __restrict__ bhh,
    float* __restrict__ cbuf, float* __restrict__ hout,
    float* yout, long y_stride)
{
    __shared__ float As[32][AS_STRIDE];
    __shared__ float Ws[32][WS_STRIDE];
    const int tid = threadIdx.x;
    const int n0 = blockIdx.x * NT;
    const int b0 = blockIdx.y * BM;
    const int tb = tid >> 3;
    const int tc = tid & 7;
    const int lr = tid >> 3;
    const int lk = tid & 7;
    const long wj = (long)(lr >> 3) * H_ + n0 + (lr & 7);
    float acc[2][4] = {{0.f, 0.f, 0.f, 0.f}, {0.f, 0.f, 0.f, 0.f}};
#pragma unroll 1
    for (int ph = 0; ph < 2; ++ph) {
        const float* Ap = (ph == 0) ? A1 : hprev;
        const long as = (ph == 0) ? a1_stride : (long)H_;
        const float* W = (ph == 0) ? Wih : Whh;
        const int K = (ph == 0) ? K1 : H_;
        const float* arow0 = Ap + (long)(b0 + lr) * as + 4 * lk;
        const float* arow1 = Ap + (long)(b0 + lr + 32) * as + 4 * lk;
        const float* wrow = W + wj * K + 4 * lk;
        float4 ra0 = *(const float4*)(arow0);
        float4 ra1 = *(const float4*)(arow1);
        float4 rw = *(const float4*)(wrow);
        for (int k0 = 0; k0 < K; k0 += 32) {
            __syncthreads();
            {
                const int kk = 4 * lk;
                As[kk + 0][lr] = ra0.x; As[kk + 1][lr] = ra0.y;
                As[kk + 2][lr] = ra0.z; As[kk + 3][lr] = ra0.w;
                As[kk + 0][lr + 32] = ra1.x; As[kk + 1][lr + 32] = ra1.y;
                As[kk + 2][lr + 32] = ra1.z; As[kk + 3][lr + 32] = ra1.w;
                Ws[kk + 0][lr] = rw.x; Ws[kk + 1][lr] = rw.y;
                Ws[kk + 2][lr] = rw.z; Ws[kk + 3][lr] = rw.w;
            }
            __syncthreads();
            const int kn = k0 + 32;
            if (kn < K) {
                ra0 = *(const float4*)(arow0 + kn);
                ra1 = *(const float4*)(arow1 + kn);
                rw = *(const float4*)(wrow + kn);
            }
#pragma unroll
            for (int k = 0; k < 32; ++k) {
                float2 a = *(const float2*)&As[k][2 * tb];
                float4 w = *(const float4*)&Ws[k][4 * tc];
                acc[0][0] = fmaf(a.x, w.x, acc[0][0]);
                acc[0][1] = fmaf(a.x, w.y, acc[0][1]);
                acc[0][2] = fmaf(a.x, w.z, acc[0][2]);
                acc[0][3] = fmaf(a.x, w.w, acc[0][3]);
                acc[1][0] = fmaf(a.y, w.x, acc[1][0]);
                acc[1][1] = fmaf(a.y, w.y, acc[1][1]);
                acc[1][2] = fmaf(a.y, w.z, acc[1][2]);
                acc[1][3] = fmaf(a.y, w.w, acc[1][3]);
            }
        }
    }
    __syncthreads();
    float* gsf = &As[0][0];
#pragma unroll
    for (int bi = 0; bi < 2; ++bi)
#pragma unroll
        for (int ci = 0; ci < 4; ++ci)
            gsf[(2 * tb + bi) * 33 + 4 * tc + ci] = acc[bi][ci];
    __syncthreads();
    const int dn = tid & 7;
    const int bq = tid >> 3;
    const int n = n0 + dn;
#pragma unroll
    for (int s = 0; s < 2; ++s) {
        const int b = bq + 32 * s;
        float xi = gsf[b * 33 + dn] + bih[n] + bhh[n];
        float xf = gsf[b * 33 + 8 + dn] + bih[H_ + n] + bhh[H_ + n];
        float xg = gsf[b * 33 + 16 + dn] + bih[2 * H_ + n] + bhh[2 * H_ + n];
        float xo = gsf[b * 33 + 24 + dn] + bih[3 * H_ + n] + bhh[3 * H_ + n];
        const long idx = (long)(b0 + b) * H_ + n;
        const float c_old = cbuf[idx];
        const float cn = fsigmoid(xf) * c_old + fsigmoid(xi) * ftanh(xg);
        const float hn = fsigmoid(xo) * ftanh(cn);
        cbuf[idx] = cn;
        hout[idx] = hn;
        if (yout) yout[(long)(b0 + b) * y_stride + n] = hn;
    }
}

extern "C" void kernel_launch(void* const* d_in, const int* in_sizes, int n_in,
                              void* d_out, int out_size, void* d_ws, size_t ws_size,
                              hipStream_t stream) {
    const float* x = (const float*)d_in[0];
    const float* Wih0 = (const float*)d_in[1];
    const float* Whh0 = (const float*)d_in[2];
    const float* bih0 = (const float*)d_in[3];
    const float* bhh0 = (const float*)d_in[4];
    const float* Wih1 = (const float*)d_in[5];
    const float* Whh1 = (const float*)d_in[6];
    const float* bih1 = (const float*)d_in[7];
    const float* bhh1 = (const float*)d_in[8];
    float* out = (float*)d_out;

    const size_t BH = (size_t)B_ * H_;
    const size_t NX = (size_t)B_ * T_ * I_;           // 16,777,216
    const size_t NW0I = (size_t)4 * H_ * I_;          // 2,097,152
    const size_t NWH = (size_t)4 * H_ * H_;           // 4,194,304

    // ws carve (bytes)
    const size_t off_xh = 0;
    const size_t off_xl = off_xh + NX * 2;
    const size_t off_w0i = off_xl + NX * 2;
    const size_t off_w0h = off_w0i + NW0I * 2;
    const size_t off_w1i = off_w0h + NWH * 2;
    const size_t off_w1h = off_w1i + NWH * 2;
    const size_t off_bs0 = off_w1h + NWH * 2;
    const size_t off_bs1 = off_bs0 + 4 * H_ * 4;
    const size_t off_h0 = off_bs1 + 4 * H_ * 4;
    const size_t off_h1 = off_h0 + 4 * BH * 2;        // 2 bufs x 2 planes
    const size_t off_c0 = off_h1 + 4 * BH * 2;
    const size_t off_c1 = off_c0 + BH * 4;
    const size_t REQ = off_c1 + BH * 4;

    char* ws = (char*)d_ws;

    if (ws_size >= REQ) {
        f16* xh = (f16*)(ws + off_xh);
        f16* xl = (f16*)(ws + off_xl);
        f16* w0i = (f16*)(ws + off_w0i);
        f16* w0h = (f16*)(ws + off_w0h);
        f16* w1i = (f16*)(ws + off_w1i);
        f16* w1h = (f16*)(ws + off_w1h);
        float* bs0 = (float*)(ws + off_bs0);
        float* bs1 = (float*)(ws + off_bs1);
        f16* h0 = (f16*)(ws + off_h0);
        f16* h1 = (f16*)(ws + off_h1);
        float* c0 = (float*)(ws + off_c0);
        float* c1 = (float*)(ws + off_c1);

        // zero h0,h1,c0,c1 (contiguous block)
        hipMemsetAsync(ws + off_h0, 0, REQ - off_h0, stream);

        dim3 cb(256);
        k_split_f16<<<2048, cb, 0, stream>>>(x, xh, xl, (int)NX);
        k_f32_to_f16<<<2048, cb, 0, stream>>>(Wih0, w0i, (int)NW0I);
        k_f32_to_f16<<<2048, cb, 0, stream>>>(Whh0, w0h, (int)NWH);
        k_f32_to_f16<<<2048, cb, 0, stream>>>(Wih1, w1i, (int)NWH);
        k_f32_to_f16<<<2048, cb, 0, stream>>>(Whh1, w1h, (int)NWH);
        k_bias_sum<<<16, cb, 0, stream>>>(bih0, bhh0, bs0, 4 * H_);
        k_bias_sum<<<16, cb, 0, stream>>>(bih1, bhh1, bs1, 4 * H_);

        for (int t = 0; t <= T_; ++t) {
            lstm_step_mfma<<<256, 256, 0, stream>>>(
                t, xh, xl, w0i, w0h, w1i, w1h, bs0, bs1, h0, h1, c0, c1, out);
        }
        return;
    }

    // ---------- fp32 fallback ----------
    float* fws = (float*)d_ws;
    float* h0a = fws;
    float* h0b = fws + BH;
    float* c0 = fws + 2 * BH;
    float* h1a = fws + 3 * BH;
    float* h1b = fws + 4 * BH;
    float* c1 = fws + 5 * BH;
    hipMemsetAsync(d_ws, 0, 6 * BH * sizeof(float), stream);

    dim3 grid(H_ / NT, B_ / BM);
    dim3 block(256);
    for (int t = 0; t < T_; ++t) {
        float* h0in = (t & 1) ? h0b : h0a;
        float* h0out = (t & 1) ? h0a : h0b;
        float* h1in = (t & 1) ? h1b : h1a;
        float* h1out = (t & 1) ? h1a : h1b;
        lstm_step<<<grid, block, 0, stream>>>(
            x + (size_t)t * I_, (long)T_ * I_, I_,
            h0in, Wih0, Whh0, bih0, bhh0, c0, h0out, nullptr, 0);
        lstm_step<<<grid, block, 0, stream>>>(
            h0out, (long)H_, H_,
            h1in, Wih1, Whh1, bih1, bhh1, c1, h1out,
            out + (size_t)t * H_, (long)T_ * H_);
    }
}

// Round 3
// 4677.457 us; speedup vs baseline: 5.8537x; 1.2447x over previous
//
#include <hip/hip_runtime.h>

#define B_ 128
#define T_ 256
#define I_ 512
#define H_ 1024

typedef _Float16 f16;
typedef _Float16 v8h __attribute__((ext_vector_type(8)));
typedef float v16f __attribute__((ext_vector_type(16)));

__device__ __forceinline__ float fsigmoid(float x) { return 1.0f / (1.0f + __expf(-x)); }
__device__ __forceinline__ float ftanh(float x) { return 1.0f - 2.0f / (__expf(2.0f * x) + 1.0f); }

__device__ __forceinline__ void gl_lds16(const void* g, void* l) {
    __builtin_amdgcn_global_load_lds(
        (const __attribute__((address_space(1))) unsigned int*)g,
        (__attribute__((address_space(3))) unsigned int*)l, 16, 0, 0);
}

// ---------------- conversion kernels ----------------
__global__ void k_f32_to_f16(const float* __restrict__ in, f16* __restrict__ out, int n) {
    int i = blockIdx.x * blockDim.x + threadIdx.x;
    int st = gridDim.x * blockDim.x;
    for (; i < n; i += st) out[i] = (f16)in[i];
}
__global__ void k_split_f16(const float* __restrict__ in, f16* __restrict__ hi,
                            f16* __restrict__ lo, int n) {
    int i = blockIdx.x * blockDim.x + threadIdx.x;
    int st = gridDim.x * blockDim.x;
    for (; i < n; i += st) {
        float v = in[i];
        f16 h = (f16)v;
        hi[i] = h;
        lo[i] = (f16)(v - (float)h);
    }
}
__global__ void k_bias_sum(const float* __restrict__ a, const float* __restrict__ b,
                           float* __restrict__ o, int n) {
    int i = blockIdx.x * blockDim.x + threadIdx.x;
    int st = gridDim.x * blockDim.x;
    for (; i < n; i += st) o[i] = a[i] + b[i];
}

// ---------------- fused MFMA step: layer0[t] (slot 0) || layer1[t-1] (slot 1) ----------------
// 512 threads / 8 waves; each wave computes the full 64x64 tile, K-split-8.
// Pipeline: global_load_lds DMA, 3 LDS buffers (chunk=128k, 48KB each), counted vmcnt(6).
__global__ __launch_bounds__(512, 1) void lstm_step2(
    int t,
    const f16* __restrict__ xh, const f16* __restrict__ xl,
    const f16* __restrict__ W0i, const f16* __restrict__ W0h,
    const f16* __restrict__ W1i, const f16* __restrict__ W1h,
    const float* __restrict__ bsum0, const float* __restrict__ bsum1,
    f16* __restrict__ h0, f16* __restrict__ h1,
    float* __restrict__ c0, float* __restrict__ c1,
    float* __restrict__ out)
{
    __shared__ __align__(16) unsigned char lds[147456];  // 3 x 48KB chunk bufs; epilogue 8x16640

    const int bx = blockIdx.x;
    const int slot = bx >> 7;
    const int m0 = ((bx >> 6) & 1) * 64;
    const int nt = bx & 63;

    if (slot == 0 && t >= T_) return;
    if (slot == 1 && t == 0) return;
    const int tau = slot ? t - 1 : t;

    const size_t BH = (size_t)B_ * H_;
    const f16 *A0h, *A0l, *A1h_, *A1l_, *Wi, *Wh;
    const float* bs;
    float* cp;
    f16 *hoh, *hol;
    float* yp = nullptr;
    long rs0;
    int K0;
    if (slot == 0) {
        A0h = xh + (size_t)tau * I_;
        A0l = xl + (size_t)tau * I_;
        rs0 = (long)T_ * I_;
        K0 = I_;
        const int pb = (tau + 1) & 1;
        A1h_ = h0 + (size_t)pb * 2 * BH;
        A1l_ = A1h_ + BH;
        Wi = W0i; Wh = W0h; bs = bsum0; cp = c0;
        f16* ob = h0 + (size_t)(tau & 1) * 2 * BH;
        hoh = ob; hol = ob + BH;
    } else {
        const int ib = tau & 1;
        A0h = h0 + (size_t)ib * 2 * BH;
        A0l = A0h + BH;
        rs0 = H_;
        K0 = H_;
        const int pb = (tau + 1) & 1;
        A1h_ = h1 + (size_t)pb * 2 * BH;
        A1l_ = A1h_ + BH;
        Wi = W1i; Wh = W1h; bs = bsum1; cp = c1;
        f16* ob = h1 + (size_t)(tau & 1) * 2 * BH;
        hoh = ob; hol = ob + BH;
        yp = out + (size_t)tau * H_;
    }

    const int tid = threadIdx.x;
    const int wave = tid >> 6;
    const int lane = tid & 63;
    const int l31 = lane & 31, khi = lane >> 5;
    const int lr4 = lane >> 4, ls = lane & 15;

    const int NC0 = K0 >> 7;       // 4 or 8
    const int NCT = NC0 + 8;       // + H/128

    // --- per-wave DMA segment bases (6 segs of 1KB per chunk per wave) ---
    // seg g = wave*6+i: plane p = g>>4 (0=A-hi,1=A-lo,2=W), q = g&15, rows q*4..q*4+3
    // lane -> row r = q*4 + (lane>>4), slot s = lane&15; source slot pre-swizzled: s ^ (r&7)
    const f16* sb0[6];
    const f16* sb1[6];
    int ldo[6];
#pragma unroll
    for (int i = 0; i < 6; ++i) {
        const int g = wave * 6 + i;
        const int p = g >> 4, q = g & 15;
        const int r = q * 4 + lr4;
        const int ss = ls ^ (r & 7);
        ldo[i] = p * 16384 + q * 1024;
        if (p == 2) {
            const size_t j = (size_t)((r >> 4) * H_ + nt * 16 + (r & 15));
            sb0[i] = Wi + j * K0 + ss * 8;
            sb1[i] = Wh + j * H_ + ss * 8;
        } else {
            const f16* a0 = p ? A0l : A0h;
            const f16* a1 = p ? A1l_ : A1h_;
            sb0[i] = a0 + (size_t)(m0 + r) * rs0 + ss * 8;
            sb1[i] = a1 + (size_t)(m0 + r) * H_ + ss * 8;
        }
    }

    auto issue = [&](int c) {
        const int bufo = (c % 3) * 49152;
        const bool ph = c >= NC0;
        const int kb = (ph ? c - NC0 : c) * 128;
#pragma unroll
        for (int i = 0; i < 6; ++i)
            gl_lds16((ph ? sb1[i] : sb0[i]) + kb, lds + bufo + ldo[i]);
    };

    // --- fragment read offsets (within a chunk buffer) ---
    const int slotk = 2 * wave + khi;                 // this wave-lane's 16B k-slot
    const int swz = (slotk ^ (l31 & 7)) * 16;
    const int offAh0 = l31 * 256 + swz;
    const int offAh1 = (l31 + 32) * 256 + swz;
    const int offAl0 = 16384 + offAh0;
    const int offAl1 = 16384 + offAh1;
    const int offB0 = 32768 + offAh0;
    const int offB1 = 32768 + offAh1;

    v16f acc00 = {}, acc01 = {}, acc10 = {}, acc11 = {};

    issue(0);
    issue(1);
    for (int c = 0; c < NCT; ++c) {
        if (c + 1 < NCT) asm volatile("s_waitcnt vmcnt(6)" ::: "memory");
        else             asm volatile("s_waitcnt vmcnt(0)" ::: "memory");
        __builtin_amdgcn_s_barrier();
        __builtin_amdgcn_sched_barrier(0);
        if (c + 2 < NCT) issue(c + 2);
        const unsigned char* bb = lds + (c % 3) * 49152;
        v8h ah0 = *(const v8h*)(bb + offAh0);
        v8h ah1 = *(const v8h*)(bb + offAh1);
        v8h al0 = *(const v8h*)(bb + offAl0);
        v8h al1 = *(const v8h*)(bb + offAl1);
        v8h b0  = *(const v8h*)(bb + offB0);
        v8h b1  = *(const v8h*)(bb + offB1);
        __builtin_amdgcn_s_setprio(1);
        acc00 = __builtin_amdgcn_mfma_f32_32x32x16_f16(ah0, b0, acc00, 0, 0, 0);
        acc00 = __builtin_amdgcn_mfma_f32_32x32x16_f16(al0, b0, acc00, 0, 0, 0);
        acc01 = __builtin_amdgcn_mfma_f32_32x32x16_f16(ah0, b1, acc01, 0, 0, 0);
        acc01 = __builtin_amdgcn_mfma_f32_32x32x16_f16(al0, b1, acc01, 0, 0, 0);
        acc10 = __builtin_amdgcn_mfma_f32_32x32x16_f16(ah1, b0, acc10, 0, 0, 0);
        acc10 = __builtin_amdgcn_mfma_f32_32x32x16_f16(al1, b0, acc10, 0, 0, 0);
        acc11 = __builtin_amdgcn_mfma_f32_32x32x16_f16(ah1, b1, acc11, 0, 0, 0);
        acc11 = __builtin_amdgcn_mfma_f32_32x32x16_f16(al1, b1, acc11, 0, 0, 0);
        __builtin_amdgcn_s_setprio(0);
    }

    // ---- epilogue: 8 K-partials -> LDS -> gather-sum -> cell update ----
    // region w at w*16640; value v (=(fm*2+fn)*16+reg) at v*260 + lane*4
    __builtin_amdgcn_s_barrier();
    {
        const unsigned base = wave * 16640 + lane * 4;
#pragma unroll
        for (int j = 0; j < 16; ++j) {
            *(float*)(lds + base + (0 * 16 + j) * 260) = acc00[j];
            *(float*)(lds + base + (1 * 16 + j) * 260) = acc01[j];
            *(float*)(lds + base + (2 * 16 + j) * 260) = acc10[j];
            *(float*)(lds + base + (3 * 16 + j) * 260) = acc11[j];
        }
    }
    __builtin_amdgcn_s_barrier();

    const int bloc = tid >> 3;          // 0..63 output row
    const int nn0 = tid & 7;
    const int b = m0 + bloc;
    const int fm = bloc >> 5;
    const int b32 = bloc & 31;
    const int rr = (b32 & 3) + 4 * (b32 >> 3);
    const int khib = (b32 >> 2) & 1;

#pragma unroll
    for (int s = 0; s < 2; ++s) {
        const int nn = nn0 + 8 * s;
        const int n = nt * 16 + nn;
        float gsum[4];
#pragma unroll
        for (int g = 0; g < 4; ++g) {
            const int cc = g * 16 + nn;
            const int fn = cc >> 5;
            const int lsrc = (cc & 31) + 32 * khib;
            const int v = (fm * 2 + fn) * 16 + rr;
            float a = 0.f;
#pragma unroll
            for (int w = 0; w < 8; ++w)
                a += *(const float*)(lds + w * 16640 + v * 260 + lsrc * 4);
            gsum[g] = a;
        }
        const float xi = gsum[0] + bs[n];
        const float xf = gsum[1] + bs[H_ + n];
        const float xg = gsum[2] + bs[2 * H_ + n];
        const float xo = gsum[3] + bs[3 * H_ + n];
        const size_t ix = (size_t)b * H_ + n;
        const float co = cp[ix];
        const float cn = fsigmoid(xf) * co + fsigmoid(xi) * ftanh(xg);
        const float hn = fsigmoid(xo) * ftanh(cn);
        cp[ix] = cn;
        const f16 hh = (f16)hn;
        hoh[ix] = hh;
        hol[ix] = (f16)(hn - (float)hh);
        if (yp) yp[(size_t)b * T_ * H_ + n] = hn;
    }
}

// ---------------- fp32 fallback (round-1 verified) ----------------
#define BM 64
#define NT 8
#define AS_STRIDE 66
#define WS_STRIDE 36

__global__ __launch_bounds__(256) void lstm_step(
    const float* __restrict__ A1, long a1_stride, int K1,
    const float* __restrict__ hprev,
    const float* __restrict__ Wih, const float* __restrict__ Whh,
    const float* __restrict__ bih, const float* __restrict__ bhh,
    float* __restrict__ cbuf, float* __restrict__ hout,
    float* yout, long y_stride)
{
    __shared__ float As[32][AS_STRIDE];
    __shared__ float Ws[32][WS_STRIDE];
    const int tid = threadIdx.x;
    const int n0 = blockIdx.x * NT;
    const int b0 = blockIdx.y * BM;
    const int tb = tid >> 3;
    const int tc = tid & 7;
    const int lr = tid >> 3;
    const int lk = tid & 7;
    const long wj = (long)(lr >> 3) * H_ + n0 + (lr & 7);
    float acc[2][4] = {{0.f, 0.f, 0.f, 0.f}, {0.f, 0.f, 0.f, 0.f}};
#pragma unroll 1
    for (int ph = 0; ph < 2; ++ph) {
        const float* Ap = (ph == 0) ? A1 : hprev;
        const long as = (ph == 0) ? a1_stride : (long)H_;
        const float* W = (ph == 0) ? Wih : Whh;
        const int K = (ph == 0) ? K1 : H_;
        const float* arow0 = Ap + (long)(b0 + lr) * as + 4 * lk;
        const float* arow1 = Ap + (long)(b0 + lr + 32) * as + 4 * lk;
        const float* wrow = W + wj * K + 4 * lk;
        float4 ra0 = *(const float4*)(arow0);
        float4 ra1 = *(const float4*)(arow1);
        float4 rw = *(const float4*)(wrow);
        for (int k0 = 0; k0 < K; k0 += 32) {
            __syncthreads();
            {
                const int kk = 4 * lk;
                As[kk + 0][lr] = ra0.x; As[kk + 1][lr] = ra0.y;
                As[kk + 2][lr] = ra0.z; As[kk + 3][lr] = ra0.w;
                As[kk + 0][lr + 32] = ra1.x; As[kk + 1][lr + 32] = ra1.y;
                As[kk + 2][lr + 32] = ra1.z; As[kk + 3][lr + 32] = ra1.w;
                Ws[kk + 0][lr] = rw.x; Ws[kk + 1][lr] = rw.y;
                Ws[kk + 2][lr] = rw.z; Ws[kk + 3][lr] = rw.w;
            }
            __syncthreads();
            const int kn = k0 + 32;
            if (kn < K) {
                ra0 = *(const float4*)(arow0 + kn);
                ra1 = *(const float4*)(arow1 + kn);
                rw = *(const float4*)(wrow + kn);
            }
#pragma unroll
            for (int k = 0; k < 32; ++k) {
                float2 a = *(const float2*)&As[k][2 * tb];
                float4 w = *(const float4*)&Ws[k][4 * tc];
                acc[0][0] = fmaf(a.x, w.x, acc[0][0]);
                acc[0][1] = fmaf(a.x, w.y, acc[0][1]);
                acc[0][2] = fmaf(a.x, w.z, acc[0][2]);
                acc[0][3] = fmaf(a.x, w.w, acc[0][3]);
                acc[1][0] = fmaf(a.y, w.x, acc[1][0]);
                acc[1][1] = fmaf(a.y, w.y, acc[1][1]);
                acc[1][2] = fmaf(a.y, w.z, acc[1][2]);
                acc[1][3] = fmaf(a.y, w.w, acc[1][3]);
            }
        }
    }
    __syncthreads();
    float* gsf = &As[0][0];
#pragma unroll
    for (int bi = 0; bi < 2; ++bi)
#pragma unroll
        for (int ci = 0; ci < 4; ++ci)
            gsf[(2 * tb + bi) * 33 + 4 * tc + ci] = acc[bi][ci];
    __syncthreads();
    const int dn = tid & 7;
    const int bq = tid >> 3;
    const int n = n0 + dn;
#pragma unroll
    for (int s = 0; s < 2; ++s) {
        const int b = bq + 32 * s;
        float xi = gsf[b * 33 + dn] + bih[n] + bhh[n];
        float xf = gsf[b * 33 + 8 + dn] + bih[H_ + n] + bhh[H_ + n];
        float xg = gsf[b * 33 + 16 + dn] + bih[2 * H_ + n] + bhh[2 * H_ + n];
        float xo = gsf[b * 33 + 24 + dn] + bih[3 * H_ + n] + bhh[3 * H_ + n];
        const long idx = (long)(b0 + b) * H_ + n;
        const float c_old = cbuf[idx];
        const float cn = fsigmoid(xf) * c_old + fsigmoid(xi) * ftanh(xg);
        const float hn = fsigmoid(xo) * ftanh(cn);
        cbuf[idx] = cn;
        hout[idx] = hn;
        if (yout) yout[(long)(b0 + b) * y_stride + n] = hn;
    }
}

extern "C" void kernel_launch(void* const* d_in, const int* in_sizes, int n_in,
                              void* d_out, int out_size, void* d_ws, size_t ws_size,
                              hipStream_t stream) {
    const float* x = (const float*)d_in[0];
    const float* Wih0 = (const float*)d_in[1];
    const float* Whh0 = (const float*)d_in[2];
    const float* bih0 = (const float*)d_in[3];
    const float* bhh0 = (const float*)d_in[4];
    const float* Wih1 = (const float*)d_in[5];
    const float* Whh1 = (const float*)d_in[6];
    const float* bih1 = (const float*)d_in[7];
    const float* bhh1 = (const float*)d_in[8];
    float* out = (float*)d_out;

    const size_t BH = (size_t)B_ * H_;
    const size_t NX = (size_t)B_ * T_ * I_;
    const size_t NW0I = (size_t)4 * H_ * I_;
    const size_t NWH = (size_t)4 * H_ * H_;

    const size_t off_xh = 0;
    const size_t off_xl = off_xh + NX * 2;
    const size_t off_w0i = off_xl + NX * 2;
    const size_t off_w0h = off_w0i + NW0I * 2;
    const size_t off_w1i = off_w0h + NWH * 2;
    const size_t off_w1h = off_w1i + NWH * 2;
    const size_t off_bs0 = off_w1h + NWH * 2;
    const size_t off_bs1 = off_bs0 + 4 * H_ * 4;
    const size_t off_h0 = off_bs1 + 4 * H_ * 4;
    const size_t off_h1 = off_h0 + 4 * BH * 2;
    const size_t off_c0 = off_h1 + 4 * BH * 2;
    const size_t off_c1 = off_c0 + BH * 4;
    const size_t REQ = off_c1 + BH * 4;

    char* ws = (char*)d_ws;

    if (ws_size >= REQ) {
        f16* xh = (f16*)(ws + off_xh);
        f16* xl = (f16*)(ws + off_xl);
        f16* w0i = (f16*)(ws + off_w0i);
        f16* w0h = (f16*)(ws + off_w0h);
        f16* w1i = (f16*)(ws + off_w1i);
        f16* w1h = (f16*)(ws + off_w1h);
        float* bs0 = (float*)(ws + off_bs0);
        float* bs1 = (float*)(ws + off_bs1);
        f16* h0 = (f16*)(ws + off_h0);
        f16* h1 = (f16*)(ws + off_h1);
        float* c0 = (float*)(ws + off_c0);
        float* c1 = (float*)(ws + off_c1);

        hipMemsetAsync(ws + off_h0, 0, REQ - off_h0, stream);

        dim3 cb(256);
        k_split_f16<<<2048, cb, 0, stream>>>(x, xh, xl, (int)NX);
        k_f32_to_f16<<<2048, cb, 0, stream>>>(Wih0, w0i, (int)NW0I);
        k_f32_to_f16<<<2048, cb, 0, stream>>>(Whh0, w0h, (int)NWH);
        k_f32_to_f16<<<2048, cb, 0, stream>>>(Wih1, w1i, (int)NWH);
        k_f32_to_f16<<<2048, cb, 0, stream>>>(Whh1, w1h, (int)NWH);
        k_bias_sum<<<16, cb, 0, stream>>>(bih0, bhh0, bs0, 4 * H_);
        k_bias_sum<<<16, cb, 0, stream>>>(bih1, bhh1, bs1, 4 * H_);

        for (int t = 0; t <= T_; ++t) {
            lstm_step2<<<256, 512, 0, stream>>>(
                t, xh, xl, w0i, w0h, w1i, w1h, bs0, bs1, h0, h1, c0, c1, out);
        }
        return;
    }

    // ---------- fp32 fallback ----------
    float* fws = (float*)d_ws;
    float* h0a = fws;
    float* h0b = fws + BH;
    float* c0 = fws + 2 * BH;
    float* h1a = fws + 3 * BH;
    float* h1b = fws + 4 * BH;
    float* c1 = fws + 5 * BH;
    hipMemsetAsync(d_ws, 0, 6 * BH * sizeof(float), stream);

    dim3 grid(H_ / NT, B_ / BM);
    dim3 block(256);
    for (int t = 0; t < T_; ++t) {
        float* h0in = (t & 1) ? h0b : h0a;
        float* h0out = (t & 1) ? h0a : h0b;
        float* h1in = (t & 1) ? h1b : h1a;
        float* h1out = (t & 1) ? h1a : h1b;
        lstm_step<<<grid, block, 0, stream>>>(
            x + (size_t)t * I_, (long)T_ * I_, I_,
            h0in, Wih0, Whh0, bih0, bhh0, c0, h0out, nullptr, 0);
        lstm_step<<<grid, block, 0, stream>>>(
            h0out, (long)H_, H_,
            h1in, Wih1, Whh1, bih1, bhh1, c1, h1out,
            out + (size_t)t * H_, (long)T_ * H_);
    }
}